// Round 1
// baseline (680.505 us; speedup 1.0000x reference)
//
#include <hip/hip_runtime.h>

typedef unsigned short u16;
typedef __bf16 bf16x8 __attribute__((ext_vector_type(8)));
typedef float f32x4 __attribute__((ext_vector_type(4)));

__device__ __forceinline__ u16 f2bf(float f) {
  union { float f; unsigned u; } v; v.f = f;
  unsigned r = v.u + 0x7FFFu + ((v.u >> 16) & 1u);
  return (u16)(r >> 16);
}

__device__ __forceinline__ void gload16(const void* g, void* l) {
  __builtin_amdgcn_global_load_lds(
      (const __attribute__((address_space(1))) unsigned int*)g,
      (__attribute__((address_space(3))) unsigned int*)l, 16, 0, 0);
}

// ---------------- fp32 -> bf16 convert (vectorized, grid-stride) -------------
__global__ __launch_bounds__(256) void cvt_bf16(const float* __restrict__ in,
                                                u16* __restrict__ out, long n) {
  long i = ((long)blockIdx.x * 256 + threadIdx.x) * 8;
  const long stride = (long)gridDim.x * 2048;
  for (; i < n; i += stride) {
    float4 a = *(const float4*)(in + i);
    float4 b = *(const float4*)(in + i + 4);
    uint4 o;
    o.x = (unsigned)f2bf(a.x) | ((unsigned)f2bf(a.y) << 16);
    o.y = (unsigned)f2bf(a.z) | ((unsigned)f2bf(a.w) << 16);
    o.z = (unsigned)f2bf(b.x) | ((unsigned)f2bf(b.y) << 16);
    o.w = (unsigned)f2bf(b.z) | ((unsigned)f2bf(b.w) << 16);
    *(uint4*)(out + i) = o;
  }
}

// ---------------- NT GEMM: C[M,N] = A[M,K] * B[N,K]^T (bf16 in, f32 acc) -----
// 128x128 tile, BK=64, 4 waves (2x2), each wave 64x64 via 16x16x32 MFMA.
template <typename OUT>
__global__ __launch_bounds__(256) void gemm_nt(const u16* __restrict__ A,
                                               const u16* __restrict__ B,
                                               OUT* __restrict__ C,
                                               int M, int N, int K) {
  __shared__ __align__(16) u16 sA[128 * 64];
  __shared__ __align__(16) u16 sB[128 * 64];
  const int tid = threadIdx.x;
  const int w = tid >> 6, ln = tid & 63;
  const int lr = ln & 15, lg = ln >> 4;
  const int bm = blockIdx.y * 128, bn = blockIdx.x * 128;
  const int wm = (w >> 1) * 64, wn = (w & 1) * 64;

  f32x4 acc[4][4] = {};

  for (int k0 = 0; k0 < K; k0 += 64) {
    __syncthreads();
#pragma unroll
    for (int i = 0; i < 4; ++i) {
      const int off = i * 4096 + tid * 16;   // byte offset in LDS tile
      const int row = off >> 7;              // /128B per row (64 bf16)
      const int cb = off & 127;
      gload16(A + (size_t)(bm + row) * K + k0 + (cb >> 1), (char*)sA + off);
      gload16(B + (size_t)(bn + row) * K + k0 + (cb >> 1), (char*)sB + off);
    }
    __syncthreads();
#pragma unroll
    for (int kk = 0; kk < 64; kk += 32) {
      bf16x8 af[4], bfr[4];
#pragma unroll
      for (int m = 0; m < 4; ++m)
        af[m] = *(const bf16x8*)&sA[(wm + m * 16 + lr) * 64 + kk + lg * 8];
#pragma unroll
      for (int n = 0; n < 4; ++n)
        bfr[n] = *(const bf16x8*)&sB[(wn + n * 16 + lr) * 64 + kk + lg * 8];
#pragma unroll
      for (int m = 0; m < 4; ++m)
#pragma unroll
        for (int n = 0; n < 4; ++n)
          acc[m][n] = __builtin_amdgcn_mfma_f32_16x16x32_bf16(af[m], bfr[n],
                                                              acc[m][n], 0, 0, 0);
    }
  }

#pragma unroll
  for (int m = 0; m < 4; ++m)
#pragma unroll
    for (int n = 0; n < 4; ++n)
#pragma unroll
      for (int r = 0; r < 4; ++r) {
        const int row = bm + wm + m * 16 + lg * 4 + r;
        const int col = bn + wn + n * 16 + lr;
        const float v = acc[m][n][r];
        if constexpr (sizeof(OUT) == 2)
          C[(size_t)row * N + col] = (OUT)f2bf(v);
        else
          C[(size_t)row * N + col] = v;
      }
}

// ---------------- V transpose: vT[hk][d][t] = qkv[t][5120 + hk*128 + d] ------
__global__ __launch_bounds__(256) void vtrans(const u16* __restrict__ qkv,
                                              u16* __restrict__ vT) {
  __shared__ u16 tile[128][65];
  const int hk = blockIdx.y;
  const int tb = blockIdx.x * 64;
  const int tid = threadIdx.x;
#pragma unroll
  for (int p = 0; p < 4; ++p) {
    const int tr = p * 16 + (tid >> 4);
    const int d0 = (tid & 15) * 8;
    const uint4 x = *(const uint4*)(qkv + (size_t)(tb + tr) * 6144 + 5120 + hk * 128 + d0);
    const u16* xv = (const u16*)&x;
#pragma unroll
    for (int j = 0; j < 8; ++j) tile[d0 + j][tr] = xv[j];
  }
  __syncthreads();
#pragma unroll
  for (int p = 0; p < 4; ++p) {
    const int d = p * 32 + (tid >> 3);
    const int t0 = (tid & 7) * 8;
    u16 v[8];
#pragma unroll
    for (int j = 0; j < 8; ++j) v[j] = tile[d][t0 + j];
    uint4 o;
    unsigned* ov = (unsigned*)&o;
#pragma unroll
    for (int j = 0; j < 4; ++j)
      ov[j] = (unsigned)v[2 * j] | ((unsigned)v[2 * j + 1] << 16);
    *(uint4*)(vT + (size_t)hk * 128 * 2048 + (size_t)d * 2048 + tb + t0) = o;
  }
}

// ---------------- flash attention (causal GQA) -------------------------------
// grid: (32 q-tiles, 32 heads); 4 waves x 16 q-rows; KV tile = 64.
__global__ __launch_bounds__(256) void attn(const u16* __restrict__ qkv,
                                            const u16* __restrict__ vT,
                                            u16* __restrict__ ctx) {
  __shared__ __align__(16) u16 sK[64 * 128];   // [kv][d], XOR-swizzled rows
  __shared__ __align__(16) u16 sV[128 * 64];   // [d][kv], XOR-swizzled rows
  __shared__ __align__(16) u16 sP[4 * 16 * 64];
  const int tid = threadIdx.x, w = tid >> 6, ln = tid & 63;
  const int lr = ln & 15, lg = ln >> 4;
  const int h = blockIdx.y, hk = h >> 2;
  const int qb = blockIdx.x, qbase = qb * 64;

  bf16x8 qf[4];
  {
    const u16* qrow = qkv + (size_t)(qbase + w * 16 + lr) * 6144 + h * 128 + lg * 8;
#pragma unroll
    for (int kk = 0; kk < 4; ++kk) qf[kk] = *(const bf16x8*)(qrow + kk * 32);
  }

  f32x4 acc_o[8] = {};
  float m_r[4] = {-INFINITY, -INFINITY, -INFINITY, -INFINITY};
  float l_r[4] = {0.f, 0.f, 0.f, 0.f};
  const float scale = 0.08838834764831845f;  // 1/sqrt(128)
  const float LOG2E = 1.4426950408889634f;
  char* const pw = (char*)sP + w * 2048;

  for (int kt = 0; kt <= qb; ++kt) {
    const int kvbase = kt * 64;
    __syncthreads();
#pragma unroll
    for (int i = 0; i < 4; ++i) {
      const int off = i * 4096 + tid * 16;
      {  // K tile: rows 256B; pre-swizzle the global source (rule #21)
        const int row = off >> 8, cbp = off & 255;
        const int cb = cbp ^ ((row & 7) << 4);
        gload16(qkv + (size_t)(kvbase + row) * 6144 + 4096 + hk * 128 + (cb >> 1),
                (char*)sK + off);
      }
      {  // V^T tile: rows 128B
        const int row = off >> 7, cbp = off & 127;
        const int cb = cbp ^ ((row & 7) << 4);
        gload16(vT + (size_t)hk * 262144 + (size_t)row * 2048 + kvbase + (cb >> 1),
                (char*)sV + off);
      }
    }
    __syncthreads();

    // S = Q K^T  (16 MFMA / wave)
    f32x4 sacc[4] = {};
#pragma unroll
    for (int kk = 0; kk < 4; ++kk) {
#pragma unroll
      for (int nf = 0; nf < 4; ++nf) {
        const int row = nf * 16 + lr;
        const int byt = row * 256 + ((kk * 64 + lg * 16) ^ ((row & 7) << 4));
        const bf16x8 kf = *(const bf16x8*)((const char*)sK + byt);
        sacc[nf] = __builtin_amdgcn_mfma_f32_16x16x32_bf16(qf[kk], kf, sacc[nf], 0, 0, 0);
      }
    }

    const bool diag = (kt == qb);
    float p[4][4];
#pragma unroll
    for (int r = 0; r < 4; ++r) {
      const int qrow = qbase + w * 16 + lg * 4 + r;
      float mx = -INFINITY;
#pragma unroll
      for (int nf = 0; nf < 4; ++nf) {
        float v = sacc[nf][r] * scale;
        if (diag && (kvbase + nf * 16 + lr > qrow)) v = -INFINITY;
        p[nf][r] = v;
        mx = fmaxf(mx, v);
      }
      mx = fmaxf(mx, __shfl_xor(mx, 1));
      mx = fmaxf(mx, __shfl_xor(mx, 2));
      mx = fmaxf(mx, __shfl_xor(mx, 4));
      mx = fmaxf(mx, __shfl_xor(mx, 8));
      const float mt = fmaxf(m_r[r], mx);
      const float alpha = exp2f((m_r[r] - mt) * LOG2E);
      m_r[r] = mt;
      float rs = 0.f;
#pragma unroll
      for (int nf = 0; nf < 4; ++nf) {
        const float e = exp2f((p[nf][r] - mt) * LOG2E);
        p[nf][r] = e;
        rs += e;
      }
      rs += __shfl_xor(rs, 1);
      rs += __shfl_xor(rs, 2);
      rs += __shfl_xor(rs, 4);
      rs += __shfl_xor(rs, 8);
      l_r[r] = l_r[r] * alpha + rs;
#pragma unroll
      for (int o = 0; o < 8; ++o) acc_o[o][r] = acc_o[o][r] * alpha;
    }

    // P -> LDS (bf16, swizzled rows), per-wave private region
#pragma unroll
    for (int r = 0; r < 4; ++r) {
      const int row = lg * 4 + r;
#pragma unroll
      for (int nf = 0; nf < 4; ++nf) {
        const int col = nf * 16 + lr;
        const int byt = row * 128 + ((2 * col) ^ ((row & 7) << 4));
        *(u16*)(pw + byt) = f2bf(p[nf][r]);
      }
    }

    // O += P V  (16 MFMA / wave)
#pragma unroll
    for (int kk2 = 0; kk2 < 2; ++kk2) {
      const int pbyt = lr * 128 + ((kk2 * 64 + lg * 16) ^ ((lr & 7) << 4));
      const bf16x8 pf = *(const bf16x8*)(pw + pbyt);
#pragma unroll
      for (int o = 0; o < 8; ++o) {
        const int vrow = o * 16 + lr;
        const int vbyt = vrow * 128 + ((kk2 * 64 + lg * 16) ^ ((vrow & 7) << 4));
        const bf16x8 vf = *(const bf16x8*)((const char*)sV + vbyt);
        acc_o[o] = __builtin_amdgcn_mfma_f32_16x16x32_bf16(pf, vf, acc_o[o], 0, 0, 0);
      }
    }
  }

#pragma unroll
  for (int r = 0; r < 4; ++r) {
    const float inv = 1.f / l_r[r];
    const int t = qbase + w * 16 + lg * 4 + r;
#pragma unroll
    for (int o = 0; o < 8; ++o)
      ctx[(size_t)t * 4096 + h * 128 + o * 16 + lr] = f2bf(acc_o[o][r] * inv);
  }
}

// ---------------- launch -----------------------------------------------------
extern "C" void kernel_launch(void* const* d_in, const int* in_sizes, int n_in,
                              void* d_out, int out_size, void* d_ws, size_t ws_size,
                              hipStream_t stream) {
  (void)in_sizes; (void)n_in; (void)out_size; (void)ws_size;
  const float* hidden = (const float*)d_in[1];
  const float* w_qkv = (const float*)d_in[2];
  const float* w_o = (const float*)d_in[3];
  float* out = (float*)d_out;
  char* ws = (char*)d_ws;

  u16* xb    = (u16*)(ws + 0);                   // 2048*4096   bf16  (16 MB)
  u16* wqkvb = (u16*)(ws + 16777216);            // 6144*4096   bf16  (48 MB)
  u16* wob   = (u16*)(ws + 67108864);            // 4096*4096   bf16  (32 MB)
  u16* qkvb  = (u16*)(ws + 100663296);           // 2048*6144   bf16  (24 MB)
  u16* vTb   = (u16*)(ws + 125829120);           // 8*128*2048  bf16  (4 MB)
  u16* ctxb  = (u16*)(ws + 130023424);           // 2048*4096   bf16  (16 MB)

  cvt_bf16<<<4096, 256, 0, stream>>>(hidden, xb, (long)2048 * 4096);
  cvt_bf16<<<8192, 256, 0, stream>>>(w_qkv, wqkvb, (long)6144 * 4096);
  cvt_bf16<<<8192, 256, 0, stream>>>(w_o, wob, (long)4096 * 4096);
  gemm_nt<u16><<<dim3(48, 16), 256, 0, stream>>>(xb, wqkvb, qkvb, 2048, 6144, 4096);
  vtrans<<<dim3(32, 8), 256, 0, stream>>>(qkvb, vTb);
  attn<<<dim3(32, 32), 256, 0, stream>>>(qkvb, vTb, ctxb);
  gemm_nt<float><<<dim3(32, 16), 256, 0, stream>>>(ctxb, wob, out, 2048, 4096, 4096);
}

// Round 2
// 437.004 us; speedup vs baseline: 1.5572x; 1.5572x over previous
//
#include <hip/hip_runtime.h>

typedef unsigned short u16;
typedef __bf16 bf16x8 __attribute__((ext_vector_type(8)));
typedef float f32x4 __attribute__((ext_vector_type(4)));

__device__ __forceinline__ u16 f2bf(float f) {
  union { float f; unsigned u; } v; v.f = f;
  unsigned r = v.u + 0x7FFFu + ((v.u >> 16) & 1u);
  return (u16)(r >> 16);
}

__device__ __forceinline__ void gload16(const void* g, void* l) {
  __builtin_amdgcn_global_load_lds(
      (const __attribute__((address_space(1))) unsigned int*)g,
      (__attribute__((address_space(3))) unsigned int*)l, 16, 0, 0);
}

// ---------------- fp32 -> bf16 convert (vectorized, grid-stride) -------------
__global__ __launch_bounds__(256) void cvt_bf16(const float* __restrict__ in,
                                                u16* __restrict__ out, long n) {
  long i = ((long)blockIdx.x * 256 + threadIdx.x) * 8;
  const long stride = (long)gridDim.x * 2048;
  for (; i < n; i += stride) {
    float4 a = *(const float4*)(in + i);
    float4 b = *(const float4*)(in + i + 4);
    uint4 o;
    o.x = (unsigned)f2bf(a.x) | ((unsigned)f2bf(a.y) << 16);
    o.y = (unsigned)f2bf(a.z) | ((unsigned)f2bf(a.w) << 16);
    o.z = (unsigned)f2bf(b.x) | ((unsigned)f2bf(b.y) << 16);
    o.w = (unsigned)f2bf(b.z) | ((unsigned)f2bf(b.w) << 16);
    *(uint4*)(out + i) = o;
  }
}

// ---------------- NT GEMM: C[M,N] = A[M,K] * B[N,K]^T (bf16 in, f32 acc) -----
template <typename OUT>
__global__ __launch_bounds__(256) void gemm_nt(const u16* __restrict__ A,
                                               const u16* __restrict__ B,
                                               OUT* __restrict__ C,
                                               int M, int N, int K) {
  __shared__ __align__(16) u16 sA[128 * 64];
  __shared__ __align__(16) u16 sB[128 * 64];
  const int tid = threadIdx.x;
  const int w = tid >> 6, ln = tid & 63;
  const int lr = ln & 15, lg = ln >> 4;
  const int bm = blockIdx.y * 128, bn = blockIdx.x * 128;
  const int wm = (w >> 1) * 64, wn = (w & 1) * 64;

  f32x4 acc[4][4] = {};

  for (int k0 = 0; k0 < K; k0 += 64) {
    __syncthreads();
#pragma unroll
    for (int i = 0; i < 4; ++i) {
      const int off = i * 4096 + tid * 16;
      const int row = off >> 7;
      const int cb = off & 127;
      gload16(A + (size_t)(bm + row) * K + k0 + (cb >> 1), (char*)sA + off);
      gload16(B + (size_t)(bn + row) * K + k0 + (cb >> 1), (char*)sB + off);
    }
    __syncthreads();
#pragma unroll
    for (int kk = 0; kk < 64; kk += 32) {
      bf16x8 af[4], bfr[4];
#pragma unroll
      for (int m = 0; m < 4; ++m)
        af[m] = *(const bf16x8*)&sA[(wm + m * 16 + lr) * 64 + kk + lg * 8];
#pragma unroll
      for (int n = 0; n < 4; ++n)
        bfr[n] = *(const bf16x8*)&sB[(wn + n * 16 + lr) * 64 + kk + lg * 8];
#pragma unroll
      for (int m = 0; m < 4; ++m)
#pragma unroll
        for (int n = 0; n < 4; ++n)
          acc[m][n] = __builtin_amdgcn_mfma_f32_16x16x32_bf16(af[m], bfr[n],
                                                              acc[m][n], 0, 0, 0);
    }
  }

#pragma unroll
  for (int m = 0; m < 4; ++m)
#pragma unroll
    for (int n = 0; n < 4; ++n)
#pragma unroll
      for (int r = 0; r < 4; ++r) {
        const int row = bm + wm + m * 16 + lg * 4 + r;
        const int col = bn + wn + n * 16 + lr;
        const float v = acc[m][n][r];
        if constexpr (sizeof(OUT) == 2)
          C[(size_t)row * N + col] = (OUT)f2bf(v);
        else
          C[(size_t)row * N + col] = v;
      }
}

// ---------------- V transpose: vT[hk][d][t] = qkv[t][5120 + hk*128 + d] ------
__global__ __launch_bounds__(256) void vtrans(const u16* __restrict__ qkv,
                                              u16* __restrict__ vT) {
  __shared__ u16 tile[128][65];
  const int hk = blockIdx.y;
  const int tb = blockIdx.x * 64;
  const int tid = threadIdx.x;
#pragma unroll
  for (int p = 0; p < 4; ++p) {
    const int tr = p * 16 + (tid >> 4);
    const int d0 = (tid & 15) * 8;
    const uint4 x = *(const uint4*)(qkv + (size_t)(tb + tr) * 6144 + 5120 + hk * 128 + d0);
    const u16* xv = (const u16*)&x;
#pragma unroll
    for (int j = 0; j < 8; ++j) tile[d0 + j][tr] = xv[j];
  }
  __syncthreads();
#pragma unroll
  for (int p = 0; p < 4; ++p) {
    const int d = p * 32 + (tid >> 3);
    const int t0 = (tid & 7) * 8;
    u16 v[8];
#pragma unroll
    for (int j = 0; j < 8; ++j) v[j] = tile[d][t0 + j];
    uint4 o;
    unsigned* ov = (unsigned*)&o;
#pragma unroll
    for (int j = 0; j < 4; ++j)
      ov[j] = (unsigned)v[2 * j] | ((unsigned)v[2 * j + 1] << 16);
    *(uint4*)(vT + (size_t)hk * 128 * 2048 + (size_t)d * 2048 + tb + t0) = o;
  }
}

// ---------------- flash attention (causal GQA), paired q-tiles + dbuf --------
// grid: (16 pair-indices, 32 heads). Block pi handles q-tiles {pi, 31-pi}
// sequentially -> uniform 33 KV-tile iterations per block (load balance).
// K/V double-buffered in LDS; stage of tile kt+1 issues before compute of kt.
__global__ __launch_bounds__(256) void attn(const u16* __restrict__ qkv,
                                            const u16* __restrict__ vT,
                                            u16* __restrict__ ctx) {
  __shared__ __align__(16) u16 sK[2][64 * 128];  // [buf][kv][d], swizzled rows
  __shared__ __align__(16) u16 sV[2][128 * 64];  // [buf][d][kv], swizzled rows
  __shared__ __align__(16) u16 sP[4 * 16 * 64];
  const int tid = threadIdx.x, w = tid >> 6, ln = tid & 63;
  const int lr = ln & 15, lg = ln >> 4;
  const int h = blockIdx.y, hk = h >> 2;
  const int pi = blockIdx.x;

  const float scale = 0.08838834764831845f;  // 1/sqrt(128)
  const float LOG2E = 1.4426950408889634f;
  char* const pw = (char*)sP + w * 2048;

  auto stage = [&](int buf, int kt) {
    const int kvbase = kt * 64;
#pragma unroll
    for (int i = 0; i < 4; ++i) {
      const int off = i * 4096 + tid * 16;
      {  // K tile: rows 256B; pre-swizzle the global source (rule #21)
        const int row = off >> 8, cbp = off & 255;
        const int cb = cbp ^ ((row & 7) << 4);
        gload16(qkv + (size_t)(kvbase + row) * 6144 + 4096 + hk * 128 + (cb >> 1),
                (char*)sK + buf * 16384 + off);
      }
      {  // V^T tile: rows 128B
        const int row = off >> 7, cbp = off & 127;
        const int cb = cbp ^ ((row & 7) << 4);
        gload16(vT + (size_t)hk * 262144 + (size_t)row * 2048 + kvbase + (cb >> 1),
                (char*)sV + buf * 16384 + off);
      }
    }
  };

#pragma unroll 1
  for (int ph = 0; ph < 2; ++ph) {
    const int qt = ph ? (31 - pi) : pi;
    const int qbase = qt * 64;
    const int nkt = qt + 1;

    bf16x8 qf[4];
    {
      const u16* qrow = qkv + (size_t)(qbase + w * 16 + lr) * 6144 + h * 128 + lg * 8;
#pragma unroll
      for (int kk = 0; kk < 4; ++kk) qf[kk] = *(const bf16x8*)(qrow + kk * 32);
    }

    f32x4 acc_o[8] = {};
    float m_r[4] = {-INFINITY, -INFINITY, -INFINITY, -INFINITY};
    float l_r[4] = {0.f, 0.f, 0.f, 0.f};

    stage(0, 0);  // prologue

#pragma unroll 1
    for (int kt = 0; kt < nkt; ++kt) {
      const int buf = kt & 1;
      const int kvbase = kt * 64;
      __syncthreads();  // drains vmcnt -> buf ready for all waves
      if (kt + 1 < nkt) stage(buf ^ 1, kt + 1);  // overlap with compute below

      char* const kbase = (char*)sK + buf * 16384;
      char* const vbase = (char*)sV + buf * 16384;

      // S = Q K^T  (16 MFMA / wave)
      f32x4 sacc[4] = {};
#pragma unroll
      for (int kk = 0; kk < 4; ++kk) {
#pragma unroll
        for (int nf = 0; nf < 4; ++nf) {
          const int row = nf * 16 + lr;
          const int byt = row * 256 + ((kk * 64 + lg * 16) ^ ((row & 7) << 4));
          const bf16x8 kf = *(const bf16x8*)(kbase + byt);
          sacc[nf] = __builtin_amdgcn_mfma_f32_16x16x32_bf16(qf[kk], kf, sacc[nf], 0, 0, 0);
        }
      }

      const bool diag = (kt == qt);
      float p[4][4];
#pragma unroll
      for (int r = 0; r < 4; ++r) {
        const int qrow = qbase + w * 16 + lg * 4 + r;
        float mx = -INFINITY;
#pragma unroll
        for (int nf = 0; nf < 4; ++nf) {
          float v = sacc[nf][r] * scale;
          if (diag && (kvbase + nf * 16 + lr > qrow)) v = -INFINITY;
          p[nf][r] = v;
          mx = fmaxf(mx, v);
        }
        mx = fmaxf(mx, __shfl_xor(mx, 1));
        mx = fmaxf(mx, __shfl_xor(mx, 2));
        mx = fmaxf(mx, __shfl_xor(mx, 4));
        mx = fmaxf(mx, __shfl_xor(mx, 8));
        const float mt = fmaxf(m_r[r], mx);
        const float alpha = exp2f((m_r[r] - mt) * LOG2E);
        m_r[r] = mt;
        float rs = 0.f;
#pragma unroll
        for (int nf = 0; nf < 4; ++nf) {
          const float e = exp2f((p[nf][r] - mt) * LOG2E);
          p[nf][r] = e;
          rs += e;
        }
        rs += __shfl_xor(rs, 1);
        rs += __shfl_xor(rs, 2);
        rs += __shfl_xor(rs, 4);
        rs += __shfl_xor(rs, 8);
        l_r[r] = l_r[r] * alpha + rs;
#pragma unroll
        for (int o = 0; o < 8; ++o) acc_o[o][r] = acc_o[o][r] * alpha;
      }

      // P -> LDS (bf16, swizzled rows), per-wave private region
#pragma unroll
      for (int r = 0; r < 4; ++r) {
        const int row = lg * 4 + r;
#pragma unroll
        for (int nf = 0; nf < 4; ++nf) {
          const int col = nf * 16 + lr;
          const int byt = row * 128 + ((2 * col) ^ ((row & 7) << 4));
          *(u16*)(pw + byt) = f2bf(p[nf][r]);
        }
      }

      // O += P V  (16 MFMA / wave)
#pragma unroll
      for (int kk2 = 0; kk2 < 2; ++kk2) {
        const int pbyt = lr * 128 + ((kk2 * 64 + lg * 16) ^ ((lr & 7) << 4));
        const bf16x8 pf = *(const bf16x8*)(pw + pbyt);
#pragma unroll
        for (int o = 0; o < 8; ++o) {
          const int vrow = o * 16 + lr;
          const int vbyt = vrow * 128 + ((kk2 * 64 + lg * 16) ^ ((vrow & 7) << 4));
          const bf16x8 vf = *(const bf16x8*)(vbase + vbyt);
          acc_o[o] = __builtin_amdgcn_mfma_f32_16x16x32_bf16(pf, vf, acc_o[o], 0, 0, 0);
        }
      }
    }

    // epilogue: normalize + store this q-tile
#pragma unroll
    for (int r = 0; r < 4; ++r) {
      const float inv = 1.f / l_r[r];
      const int t = qbase + w * 16 + lg * 4 + r;
#pragma unroll
      for (int o = 0; o < 8; ++o)
        ctx[(size_t)t * 4096 + h * 128 + o * 16 + lr] = f2bf(acc_o[o][r] * inv);
    }
    __syncthreads();  // all waves done reading buffers before next phase stages
  }
}

// ---------------- launch -----------------------------------------------------
extern "C" void kernel_launch(void* const* d_in, const int* in_sizes, int n_in,
                              void* d_out, int out_size, void* d_ws, size_t ws_size,
                              hipStream_t stream) {
  (void)in_sizes; (void)n_in; (void)out_size; (void)ws_size;
  const float* hidden = (const float*)d_in[1];
  const float* w_qkv = (const float*)d_in[2];
  const float* w_o = (const float*)d_in[3];
  float* out = (float*)d_out;
  char* ws = (char*)d_ws;

  u16* xb    = (u16*)(ws + 0);                   // 2048*4096   bf16  (16 MB)
  u16* wqkvb = (u16*)(ws + 16777216);            // 6144*4096   bf16  (48 MB)
  u16* wob   = (u16*)(ws + 67108864);            // 4096*4096   bf16  (32 MB)
  u16* qkvb  = (u16*)(ws + 100663296);           // 2048*6144   bf16  (24 MB)
  u16* vTb   = (u16*)(ws + 125829120);           // 8*128*2048  bf16  (4 MB)
  u16* ctxb  = (u16*)(ws + 130023424);           // 2048*4096   bf16  (16 MB)

  cvt_bf16<<<4096, 256, 0, stream>>>(hidden, xb, (long)2048 * 4096);
  cvt_bf16<<<8192, 256, 0, stream>>>(w_qkv, wqkvb, (long)6144 * 4096);
  cvt_bf16<<<8192, 256, 0, stream>>>(w_o, wob, (long)4096 * 4096);
  gemm_nt<u16><<<dim3(48, 16), 256, 0, stream>>>(xb, wqkvb, qkvb, 2048, 6144, 4096);
  vtrans<<<dim3(32, 8), 256, 0, stream>>>(qkvb, vTb);
  attn<<<dim3(16, 32), 256, 0, stream>>>(qkvb, vTb, ctxb);
  gemm_nt<float><<<dim3(32, 16), 256, 0, stream>>>(ctxb, wob, out, 2048, 4096, 4096);
}

// Round 3
// 350.950 us; speedup vs baseline: 1.9390x; 1.2452x over previous
//
#include <hip/hip_runtime.h>

typedef unsigned short u16;
typedef __bf16 bf16x8 __attribute__((ext_vector_type(8)));
typedef float f32x4 __attribute__((ext_vector_type(4)));

__device__ __forceinline__ u16 f2bf(float f) {
  union { float f; unsigned u; } v; v.f = f;
  unsigned r = v.u + 0x7FFFu + ((v.u >> 16) & 1u);
  return (u16)(r >> 16);
}

__device__ __forceinline__ void gload16(const void* g, void* l) {
  __builtin_amdgcn_global_load_lds(
      (const __attribute__((address_space(1))) unsigned int*)g,
      (__attribute__((address_space(3))) unsigned int*)l, 16, 0, 0);
}

// ---------------- fp32 -> bf16 convert (vectorized, grid-stride) -------------
__global__ __launch_bounds__(256) void cvt_bf16(const float* __restrict__ in,
                                                u16* __restrict__ out, long n) {
  long i = ((long)blockIdx.x * 256 + threadIdx.x) * 8;
  const long stride = (long)gridDim.x * 2048;
  for (; i < n; i += stride) {
    float4 a = *(const float4*)(in + i);
    float4 b = *(const float4*)(in + i + 4);
    uint4 o;
    o.x = (unsigned)f2bf(a.x) | ((unsigned)f2bf(a.y) << 16);
    o.y = (unsigned)f2bf(a.z) | ((unsigned)f2bf(a.w) << 16);
    o.z = (unsigned)f2bf(b.x) | ((unsigned)f2bf(b.y) << 16);
    o.w = (unsigned)f2bf(b.z) | ((unsigned)f2bf(b.w) << 16);
    *(uint4*)(out + i) = o;
  }
}

// ---------------- NT GEMM: C[M,N] = A[M,K] * B[N,K]^T (bf16 in, f32 acc) -----
// 128x128 tile, BK=64, 4 waves (2x2). Double-buffered LDS with stage-ahead
// (one barrier per K-step) + both-sides XOR swizzle (rule #21) to kill the
// 16-way bank conflict on 128B-row fragment reads.
template <typename OUT>
__global__ __launch_bounds__(256) void gemm_nt(const u16* __restrict__ A,
                                               const u16* __restrict__ B,
                                               OUT* __restrict__ C,
                                               int M, int N, int K) {
  __shared__ __align__(16) u16 sA[2][128 * 64];
  __shared__ __align__(16) u16 sB[2][128 * 64];
  const int tid = threadIdx.x;
  const int w = tid >> 6, ln = tid & 63;
  const int lr = ln & 15, lg = ln >> 4;
  const int bm = blockIdx.y * 128, bn = blockIdx.x * 128;
  const int wm = (w >> 1) * 64, wn = (w & 1) * 64;

  f32x4 acc[4][4] = {};

  auto stage = [&](int buf, int t) {
    const int k0 = t << 6;
#pragma unroll
    for (int i = 0; i < 4; ++i) {
      const int off = i * 4096 + tid * 16;          // byte offset in LDS tile
      const int row = off >> 7;                     // 128B per row (64 bf16)
      const int cb = (off & 127) ^ ((row & 7) << 4); // pre-swizzled source col
      gload16(A + (size_t)(bm + row) * K + k0 + (cb >> 1), (char*)sA[buf] + off);
      gload16(B + (size_t)(bn + row) * K + k0 + (cb >> 1), (char*)sB[buf] + off);
    }
  };

  auto compute = [&](int buf) {
#pragma unroll
    for (int kk = 0; kk < 64; kk += 32) {
      bf16x8 af[4], bfr[4];
#pragma unroll
      for (int m = 0; m < 4; ++m) {
        const int row = wm + m * 16 + lr;
        const int byt = row * 128 + ((kk * 2 + lg * 16) ^ ((row & 7) << 4));
        af[m] = *(const bf16x8*)((const char*)sA[buf] + byt);
      }
#pragma unroll
      for (int n = 0; n < 4; ++n) {
        const int row = wn + n * 16 + lr;
        const int byt = row * 128 + ((kk * 2 + lg * 16) ^ ((row & 7) << 4));
        bfr[n] = *(const bf16x8*)((const char*)sB[buf] + byt);
      }
#pragma unroll
      for (int m = 0; m < 4; ++m)
#pragma unroll
        for (int n = 0; n < 4; ++n)
          acc[m][n] = __builtin_amdgcn_mfma_f32_16x16x32_bf16(af[m], bfr[n],
                                                              acc[m][n], 0, 0, 0);
    }
  };

  const int nk = K >> 6;
  stage(0, 0);
#pragma unroll 1
  for (int t = 0; t < nk; t += 2) {
    __syncthreads();                      // drains stage(buf0) + prior reads
    if (t + 1 < nk) stage(1, t + 1);      // in flight during compute(0)
    compute(0);
    __syncthreads();                      // drains stage(buf1) + buf0 reads
    if (t + 2 < nk) stage(0, t + 2);      // in flight during compute(1)
    if (t + 1 < nk) compute(1);
  }

#pragma unroll
  for (int m = 0; m < 4; ++m)
#pragma unroll
    for (int n = 0; n < 4; ++n)
#pragma unroll
      for (int r = 0; r < 4; ++r) {
        const int row = bm + wm + m * 16 + lg * 4 + r;
        const int col = bn + wn + n * 16 + lr;
        const float v = acc[m][n][r];
        if constexpr (sizeof(OUT) == 2)
          C[(size_t)row * N + col] = (OUT)f2bf(v);
        else
          C[(size_t)row * N + col] = v;
      }
}

// ---------------- V transpose: vT[hk][d][t] = qkv[t][5120 + hk*128 + d] ------
__global__ __launch_bounds__(256) void vtrans(const u16* __restrict__ qkv,
                                              u16* __restrict__ vT) {
  __shared__ u16 tile[128][65];
  const int hk = blockIdx.y;
  const int tb = blockIdx.x * 64;
  const int tid = threadIdx.x;
#pragma unroll
  for (int p = 0; p < 4; ++p) {
    const int tr = p * 16 + (tid >> 4);
    const int d0 = (tid & 15) * 8;
    const uint4 x = *(const uint4*)(qkv + (size_t)(tb + tr) * 6144 + 5120 + hk * 128 + d0);
    const u16* xv = (const u16*)&x;
#pragma unroll
    for (int j = 0; j < 8; ++j) tile[d0 + j][tr] = xv[j];
  }
  __syncthreads();
#pragma unroll
  for (int p = 0; p < 4; ++p) {
    const int d = p * 32 + (tid >> 3);
    const int t0 = (tid & 7) * 8;
    u16 v[8];
#pragma unroll
    for (int j = 0; j < 8; ++j) v[j] = tile[d][t0 + j];
    uint4 o;
    unsigned* ov = (unsigned*)&o;
#pragma unroll
    for (int j = 0; j < 4; ++j)
      ov[j] = (unsigned)v[2 * j] | ((unsigned)v[2 * j + 1] << 16);
    *(uint4*)(vT + (size_t)hk * 128 * 2048 + (size_t)d * 2048 + tb + t0) = o;
  }
}

// ---------------- flash attention (causal GQA), paired q-tiles + dbuf --------
__global__ __launch_bounds__(256) void attn(const u16* __restrict__ qkv,
                                            const u16* __restrict__ vT,
                                            u16* __restrict__ ctx) {
  __shared__ __align__(16) u16 sK[2][64 * 128];
  __shared__ __align__(16) u16 sV[2][128 * 64];
  __shared__ __align__(16) u16 sP[4 * 16 * 64];
  const int tid = threadIdx.x, w = tid >> 6, ln = tid & 63;
  const int lr = ln & 15, lg = ln >> 4;
  const int h = blockIdx.y, hk = h >> 2;
  const int pi = blockIdx.x;

  const float scale = 0.08838834764831845f;  // 1/sqrt(128)
  const float LOG2E = 1.4426950408889634f;
  char* const pw = (char*)sP + w * 2048;

  auto stage = [&](int buf, int kt) {
    const int kvbase = kt * 64;
#pragma unroll
    for (int i = 0; i < 4; ++i) {
      const int off = i * 4096 + tid * 16;
      {
        const int row = off >> 8, cbp = off & 255;
        const int cb = cbp ^ ((row & 7) << 4);
        gload16(qkv + (size_t)(kvbase + row) * 6144 + 4096 + hk * 128 + (cb >> 1),
                (char*)sK + buf * 16384 + off);
      }
      {
        const int row = off >> 7, cbp = off & 127;
        const int cb = cbp ^ ((row & 7) << 4);
        gload16(vT + (size_t)hk * 262144 + (size_t)row * 2048 + kvbase + (cb >> 1),
                (char*)sV + buf * 16384 + off);
      }
    }
  };

#pragma unroll 1
  for (int ph = 0; ph < 2; ++ph) {
    const int qt = ph ? (31 - pi) : pi;
    const int qbase = qt * 64;
    const int nkt = qt + 1;

    bf16x8 qf[4];
    {
      const u16* qrow = qkv + (size_t)(qbase + w * 16 + lr) * 6144 + h * 128 + lg * 8;
#pragma unroll
      for (int kk = 0; kk < 4; ++kk) qf[kk] = *(const bf16x8*)(qrow + kk * 32);
    }

    f32x4 acc_o[8] = {};
    float m_r[4] = {-INFINITY, -INFINITY, -INFINITY, -INFINITY};
    float l_r[4] = {0.f, 0.f, 0.f, 0.f};

    stage(0, 0);

#pragma unroll 1
    for (int kt = 0; kt < nkt; ++kt) {
      const int buf = kt & 1;
      const int kvbase = kt * 64;
      __syncthreads();
      if (kt + 1 < nkt) stage(buf ^ 1, kt + 1);

      char* const kbase = (char*)sK + buf * 16384;
      char* const vbase = (char*)sV + buf * 16384;

      f32x4 sacc[4] = {};
#pragma unroll
      for (int kk = 0; kk < 4; ++kk) {
#pragma unroll
        for (int nf = 0; nf < 4; ++nf) {
          const int row = nf * 16 + lr;
          const int byt = row * 256 + ((kk * 64 + lg * 16) ^ ((row & 7) << 4));
          const bf16x8 kf = *(const bf16x8*)(kbase + byt);
          sacc[nf] = __builtin_amdgcn_mfma_f32_16x16x32_bf16(qf[kk], kf, sacc[nf], 0, 0, 0);
        }
      }

      const bool diag = (kt == qt);
      float p[4][4];
#pragma unroll
      for (int r = 0; r < 4; ++r) {
        const int qrow = qbase + w * 16 + lg * 4 + r;
        float mx = -INFINITY;
#pragma unroll
        for (int nf = 0; nf < 4; ++nf) {
          float v = sacc[nf][r] * scale;
          if (diag && (kvbase + nf * 16 + lr > qrow)) v = -INFINITY;
          p[nf][r] = v;
          mx = fmaxf(mx, v);
        }
        mx = fmaxf(mx, __shfl_xor(mx, 1));
        mx = fmaxf(mx, __shfl_xor(mx, 2));
        mx = fmaxf(mx, __shfl_xor(mx, 4));
        mx = fmaxf(mx, __shfl_xor(mx, 8));
        const float mt = fmaxf(m_r[r], mx);
        const float alpha = exp2f((m_r[r] - mt) * LOG2E);
        m_r[r] = mt;
        float rs = 0.f;
#pragma unroll
        for (int nf = 0; nf < 4; ++nf) {
          const float e = exp2f((p[nf][r] - mt) * LOG2E);
          p[nf][r] = e;
          rs += e;
        }
        rs += __shfl_xor(rs, 1);
        rs += __shfl_xor(rs, 2);
        rs += __shfl_xor(rs, 4);
        rs += __shfl_xor(rs, 8);
        l_r[r] = l_r[r] * alpha + rs;
#pragma unroll
        for (int o = 0; o < 8; ++o) acc_o[o][r] = acc_o[o][r] * alpha;
      }

#pragma unroll
      for (int r = 0; r < 4; ++r) {
        const int row = lg * 4 + r;
#pragma unroll
        for (int nf = 0; nf < 4; ++nf) {
          const int col = nf * 16 + lr;
          const int byt = row * 128 + ((2 * col) ^ ((row & 7) << 4));
          *(u16*)(pw + byt) = f2bf(p[nf][r]);
        }
      }

#pragma unroll
      for (int kk2 = 0; kk2 < 2; ++kk2) {
        const int pbyt = lr * 128 + ((kk2 * 64 + lg * 16) ^ ((lr & 7) << 4));
        const bf16x8 pf = *(const bf16x8*)(pw + pbyt);
#pragma unroll
        for (int o = 0; o < 8; ++o) {
          const int vrow = o * 16 + lr;
          const int vbyt = vrow * 128 + ((kk2 * 64 + lg * 16) ^ ((vrow & 7) << 4));
          const bf16x8 vf = *(const bf16x8*)(vbase + vbyt);
          acc_o[o] = __builtin_amdgcn_mfma_f32_16x16x32_bf16(pf, vf, acc_o[o], 0, 0, 0);
        }
      }
    }

#pragma unroll
    for (int r = 0; r < 4; ++r) {
      const float inv = 1.f / l_r[r];
      const int t = qbase + w * 16 + lg * 4 + r;
#pragma unroll
      for (int o = 0; o < 8; ++o)
        ctx[(size_t)t * 4096 + h * 128 + o * 16 + lr] = f2bf(acc_o[o][r] * inv);
    }
    __syncthreads();
  }
}

// ---------------- launch -----------------------------------------------------
extern "C" void kernel_launch(void* const* d_in, const int* in_sizes, int n_in,
                              void* d_out, int out_size, void* d_ws, size_t ws_size,
                              hipStream_t stream) {
  (void)in_sizes; (void)n_in; (void)out_size; (void)ws_size;
  const float* hidden = (const float*)d_in[1];
  const float* w_qkv = (const float*)d_in[2];
  const float* w_o = (const float*)d_in[3];
  float* out = (float*)d_out;
  char* ws = (char*)d_ws;

  u16* xb    = (u16*)(ws + 0);                   // 2048*4096   bf16  (16 MB)
  u16* wqkvb = (u16*)(ws + 16777216);            // 6144*4096   bf16  (48 MB)
  u16* wob   = (u16*)(ws + 67108864);            // 4096*4096   bf16  (32 MB)
  u16* qkvb  = (u16*)(ws + 100663296);           // 2048*6144   bf16  (24 MB)
  u16* vTb   = (u16*)(ws + 125829120);           // 8*128*2048  bf16  (4 MB)
  u16* ctxb  = (u16*)(ws + 130023424);           // 2048*4096   bf16  (16 MB)

  cvt_bf16<<<4096, 256, 0, stream>>>(hidden, xb, (long)2048 * 4096);
  cvt_bf16<<<8192, 256, 0, stream>>>(w_qkv, wqkvb, (long)6144 * 4096);
  cvt_bf16<<<8192, 256, 0, stream>>>(w_o, wob, (long)4096 * 4096);
  gemm_nt<u16><<<dim3(48, 16), 256, 0, stream>>>(xb, wqkvb, qkvb, 2048, 6144, 4096);
  vtrans<<<dim3(32, 8), 256, 0, stream>>>(qkvb, vTb);
  attn<<<dim3(16, 32), 256, 0, stream>>>(qkvb, vTb, ctxb);
  gemm_nt<float><<<dim3(32, 16), 256, 0, stream>>>(ctxb, wob, out, 2048, 4096, 4096);
}